// Round 19
// baseline (239.478 us; speedup 1.0000x reference)
//
#include <hip/hip_runtime.h>
#include <hip/hip_bf16.h>
#include <math.h>

typedef __hip_bfloat16 bf16;
typedef unsigned short u16;
typedef unsigned int u32;
typedef __attribute__((ext_vector_type(8))) short bf16x8;
typedef __attribute__((ext_vector_type(4))) float f32x4;

#define LL 36864  // L*L

__device__ __forceinline__ float wave_sum(float v) {
#pragma unroll
  for (int m = 32; m; m >>= 1) v += __shfl_xor(v, m, 64);
  return v;
}

__device__ __forceinline__ float bf2f(u16 u) {
  union { float f; u32 u; } c; c.u = ((u32)u) << 16; return c.f;
}
__device__ __forceinline__ u16 f2bf(float f) {  // RNE
  union { float f; u32 u; } c; c.f = f;
  u32 r = c.u + 0x7fffu + ((c.u >> 16) & 1u);
  return (u16)(r >> 16);
}

// ---------------- kernel 0a: Wq|Wk|Wv|Wg -> Wcat[jg][128] bf16 ----------------
__global__ __launch_bounds__(256) void k_cvt(const float* __restrict__ Wq,
                                             const float* __restrict__ Wk,
                                             const float* __restrict__ Wv,
                                             const float* __restrict__ Wg,
                                             bf16* __restrict__ Wcat) {
  int u = blockIdx.x * 256 + threadIdx.x;   // 18432 tasks
  if (u >= 18432) return;
  int jg = u >> 4, k0 = (u & 15) * 8;
  int sec = jg / 288, j = jg % 288;
  const float* W = sec == 0 ? Wq : sec == 1 ? Wk : sec == 2 ? Wv : Wg;
  u16 pk[8];
#pragma unroll
  for (int i = 0; i < 8; ++i) pk[i] = f2bf(W[(size_t)(k0 + i) * 288 + j]);
  *reinterpret_cast<uint4*>(&Wcat[(size_t)jg * 128 + k0]) = *reinterpret_cast<uint4*>(pk);
}

// ---------------- kernel 0b: Wo -> Wot[n][288] bf16 ----------------
__global__ __launch_bounds__(256) void k_cvt2(const float* __restrict__ Wo,
                                              bf16* __restrict__ Wot) {
  int u = blockIdx.x * 256 + threadIdx.x;   // 4608 tasks
  if (u >= 4608) return;
  int n = u / 36, k0 = (u % 36) * 8;
  u16 pk[8];
#pragma unroll
  for (int i = 0; i < 8; ++i) pk[i] = f2bf(Wo[(size_t)(k0 + i) * 128 + n]);
  *reinterpret_cast<uint4*>(&Wot[(size_t)n * 288 + k0]) = *reinterpret_cast<uint4*>(pk);
}

// ---------------- kernel 1: LayerNorm (pure) ----------------
__global__ __launch_bounds__(256) void k_ln(const float* __restrict__ zin,
                                            const float* __restrict__ w_,
                                            const float* __restrict__ b_,
                                            bf16* __restrict__ zb) {
  int t = threadIdx.x;
  int wv = t >> 6, lane = t & 63;
  size_t m = (size_t)blockIdx.x * 4 + wv;
  const float2 v = *reinterpret_cast<const float2*>(&zin[m * 128 + lane * 2]);
  float s = wave_sum(v.x + v.y);
  float ss = wave_sum(v.x * v.x + v.y * v.y);
  float mean = s * (1.0f / 128.0f);
  float var = ss * (1.0f / 128.0f) - mean * mean;
  float rs = rsqrtf(var + 1e-5f);
  float o0 = (v.x - mean) * rs * w_[lane * 2] + b_[lane * 2];
  float o1 = (v.y - mean) * rs * w_[lane * 2 + 1] + b_[lane * 2 + 1];
  u32 pk = (u32)f2bf(o0) | ((u32)f2bf(o1) << 16);
  *reinterpret_cast<u32*>(&zb[m * 128 + lane * 2]) = pk;
}

// ---------------- kernel 1b: bias projection via MFMA ----------------
// biasT[h][l][(kk&15)*12 + (kk>>4)] = (zb @ Wb)[m= kk*192+l][h] + bb[h]
__global__ __launch_bounds__(256) void k_bias(const bf16* __restrict__ zb,
                                              const float* __restrict__ Wb,
                                              const float* __restrict__ bbv,
                                              float* __restrict__ biasb) {
  int t = threadIdx.x;
  int w = t >> 6, lane = t & 63;
  int c15 = lane & 15, g = lane >> 4;
  int m0 = (blockIdx.x * 4 + w) * 16;
  f32x4 acc = (f32x4){0.f, 0.f, 0.f, 0.f};
#pragma unroll
  for (int kt = 0; kt < 4; ++kt) {
    bf16x8 a = *reinterpret_cast<const bf16x8*>(
        &zb[(size_t)(m0 + c15) * 128 + kt * 32 + g * 8]);
    u16 bp[8];
#pragma unroll
    for (int j = 0; j < 8; ++j)
      bp[j] = (c15 < 12) ? f2bf(Wb[(size_t)(kt * 32 + g * 8 + j) * 12 + c15]) : (u16)0;
    bf16x8 b = *reinterpret_cast<bf16x8*>(bp);
    acc = __builtin_amdgcn_mfma_f32_16x16x32_bf16(a, b, acc, 0, 0, 0);
  }
  if (c15 < 12) {
    int kk = m0 / 192, l0 = m0 % 192;
    int p = (kk & 15) * 12 + (kk >> 4);
    float bv = bbv[c15];
#pragma unroll
    for (int i = 0; i < 4; ++i) {
      int l = l0 + 4 * g + i;
      biasb[(size_t)c15 * LL + (size_t)l * 192 + p] = acc[i] + bv;
    }
  }
}

// ---------------- kernel 2: projections (MFMA, 192x96 tiles, LDS-bounced stores) ----
__global__ __launch_bounds__(256) void k_proj(const bf16* __restrict__ zb,
    const bf16* __restrict__ Wcat,
    const float* __restrict__ bq, const float* __restrict__ bk,
    const float* __restrict__ bv, const float* __restrict__ bg,
    bf16* __restrict__ q2, bf16* __restrict__ k2,
    bf16* __restrict__ vb, bf16* __restrict__ gbuf) {
  __shared__ __align__(16) u16 Sb[192 * 104];
  int t = threadIdx.x;
  int w = t >> 6, lane = t & 63;
  int c15 = lane & 15, g = lane >> 4;
  int wm = w & 1, wn = w >> 1;
  int bx = blockIdx.x, y = blockIdx.y;
  int sec = y / 3, h0 = (y % 3) * 4;
  int m0 = bx * 192;
  int jbase = y * 96;
  f32x4 acc[6][3];
#pragma unroll
  for (int mt = 0; mt < 6; ++mt)
#pragma unroll
    for (int nt = 0; nt < 3; ++nt) acc[mt][nt] = (f32x4){0.f, 0.f, 0.f, 0.f};
#pragma unroll
  for (int kt = 0; kt < 4; ++kt) {
    bf16x8 a[6], b[3];
#pragma unroll
    for (int mt = 0; mt < 6; ++mt)
      a[mt] = *reinterpret_cast<const bf16x8*>(
          &zb[(size_t)(m0 + wm * 96 + mt * 16 + c15) * 128 + kt * 32 + g * 8]);
#pragma unroll
    for (int nt = 0; nt < 3; ++nt)
      b[nt] = *reinterpret_cast<const bf16x8*>(
          &Wcat[(size_t)(jbase + wn * 48 + nt * 16 + c15) * 128 + kt * 32 + g * 8]);
#pragma unroll
    for (int mt = 0; mt < 6; ++mt)
#pragma unroll
      for (int nt = 0; nt < 3; ++nt)
        acc[mt][nt] = __builtin_amdgcn_mfma_f32_16x16x32_bf16(a[mt], b[nt], acc[mt][nt], 0, 0, 0);
  }
  const float* barr = sec == 0 ? bq : sec == 1 ? bk : sec == 2 ? bv : bg;
#pragma unroll
  for (int nt = 0; nt < 3; ++nt) {
    int col = wn * 48 + nt * 16 + c15;
    float bval = barr[(y % 3) * 96 + col];
#pragma unroll
    for (int mt = 0; mt < 6; ++mt) {
      int rbase = wm * 96 + mt * 16 + 4 * g;
#pragma unroll
      for (int i = 0; i < 4; ++i)
        Sb[(rbase + i) * 104 + col] = f2bf(acc[mt][nt][i] + bval);
    }
  }
  __syncthreads();
  if (sec == 0) {
    bf16* dst0 = q2 + ((size_t)bx * 12 + h0) * 4608;
    for (int u = t; u < 2304; u += 256) {
      int hl = u / 576, off = (u % 576) * 8;
      int ml = off / 24, c0 = off % 24;
      uint4 val = *reinterpret_cast<const uint4*>(&Sb[ml * 104 + hl * 24 + c0]);
      *reinterpret_cast<uint4*>(&dst0[(size_t)hl * 4608 + off]) = val;
    }
  } else if (sec == 3) {
    for (int u = t; u < 2304; u += 256) {
      int ml = u / 12, col = (u % 12) * 8;
      uint4 val = *reinterpret_cast<const uint4*>(&Sb[ml * 104 + col]);
      *reinterpret_cast<uint4*>(&gbuf[(size_t)(m0 + ml) * 288 + h0 * 24 + col]) = val;
    }
  } else {
    bf16* dst = (sec == 1) ? k2 : vb;
    for (int u = t; u < 2304; u += 256) {
      int hl = u / 576, off = (u % 576) * 8;
      int ml = off / 24, c0 = off % 24;
      uint4 val = *reinterpret_cast<const uint4*>(&Sb[ml * 104 + hl * 24 + c0]);
      *reinterpret_cast<uint4*>(
          &dst[(((size_t)ml * 12 + h0 + hl) * 192 + bx) * 24 + c0]) = val;
    }
  }
}

// ---------------- kernel 3: attention, role = (blockIdx.z < ZA ? att : pv) --------
// att role: wave=(bq,h) via x*4+w (x<48); z-slice covers NT l-tiles at la0+z*NT*16
// pv role: x -> l = lp0+x (x<NL), h; 4 waves split 192 b-rows; Ob bounce; gated store
__global__ __launch_bounds__(256) void k_attpv(const bf16* __restrict__ q2,
    const bf16* __restrict__ k2, const float* __restrict__ biasb,
    const bf16* __restrict__ vbuf, const bf16* __restrict__ gbuf,
    bf16* __restrict__ Patt, const bf16* __restrict__ Ppv,
    bf16* __restrict__ ogb, int la0, int lp0, int NT, int NL, int ZA) {
  __shared__ __align__(16) char ldsraw[25600];
  int t = threadIdx.x;
  int w = t >> 6, lane = t & 63;
  int c15 = lane & 15, g = lane >> 4;
  const float sq_c = 0.20412414523193154f;  // 1/sqrt(24)
  bool is_att = ((int)blockIdx.z < ZA);
  if (is_att) {
    int x = blockIdx.x, h = blockIdx.y;
    if (x >= 48) return;
    int bq = x * 4 + w;
    int lbase = la0 + blockIdx.z * NT * 16;
    u16* Sb = reinterpret_cast<u16*>(ldsraw) + (size_t)w * 3200;  // per-wave [16][200]
    const bf16* ks = &k2[((size_t)bq * 12 + h) * 4608];
    const float* bsrc = &biasb[(size_t)h * LL];
    for (int lt = 0; lt < NT; ++lt) {
      int l0 = lbase + lt * 16;
      const bf16* qs = &q2[(((size_t)bq * 12 + h) * 192 + l0) * 24];
      bf16x8 afr = {0, 0, 0, 0, 0, 0, 0, 0};
      if (g < 3) afr = *reinterpret_cast<const bf16x8*>(&qs[c15 * 24 + g * 8]);
      f32x4 acc[12];
#pragma unroll
      for (int ct = 0; ct < 12; ++ct) {
        bf16x8 bfr = {0, 0, 0, 0, 0, 0, 0, 0};
        if (g < 3) bfr = *reinterpret_cast<const bf16x8*>(&ks[(ct * 16 + c15) * 24 + g * 8]);
        acc[ct] = __builtin_amdgcn_mfma_f32_16x16x32_bf16(afr, bfr, (f32x4){0.f, 0.f, 0.f, 0.f}, 0, 0, 0);
      }
      // bias: lane c15 reads 12 contiguous floats per row (transposed layout)
#pragma unroll
      for (int i = 0; i < 4; ++i) {
        const float* bT = &bsrc[(size_t)(l0 + 4 * g + i) * 192 + c15 * 12];
        float4 b0 = *reinterpret_cast<const float4*>(&bT[0]);
        float4 b1 = *reinterpret_cast<const float4*>(&bT[4]);
        float4 b2 = *reinterpret_cast<const float4*>(&bT[8]);
        float bb12[12] = {b0.x, b0.y, b0.z, b0.w, b1.x, b1.y, b1.z, b1.w,
                          b2.x, b2.y, b2.z, b2.w};
#pragma unroll
        for (int ct = 0; ct < 12; ++ct)
          acc[ct][i] = acc[ct][i] * sq_c + bb12[ct];
      }
      float inv[4];
#pragma unroll
      for (int i = 0; i < 4; ++i) {
        float mx = -1e30f;
#pragma unroll
        for (int ct = 0; ct < 12; ++ct) mx = fmaxf(mx, acc[ct][i]);
#pragma unroll
        for (int msk = 1; msk < 16; msk <<= 1) mx = fmaxf(mx, __shfl_xor(mx, msk, 64));
        float sm = 0.f;
#pragma unroll
        for (int ct = 0; ct < 12; ++ct) {
          float e = __expf(acc[ct][i] - mx);
          acc[ct][i] = e;
          sm += e;
        }
#pragma unroll
        for (int msk = 1; msk < 16; msk <<= 1) sm += __shfl_xor(sm, msk, 64);
        inv[i] = 1.0f / sm;
      }
#pragma unroll
      for (int i = 0; i < 4; ++i)
#pragma unroll
        for (int ct = 0; ct < 12; ++ct)
          Sb[(4 * g + i) * 200 + ct * 16 + c15] = f2bf(acc[ct][i] * inv[i]);
      int lrel = l0 - la0;
      for (int u = lane; u < 384; u += 64) {
        int lloc = u / 24, oct = u % 24;
        uint4 val = *reinterpret_cast<const uint4*>(&Sb[lloc * 200 + oct * 8]);
        *reinterpret_cast<uint4*>(
            &Patt[(((size_t)(lrel + lloc) * 12 + h) * 192 + bq) * 192 + oct * 8]) = val;
      }
    }
  } else {
    if (lp0 < 0) return;
    int x = blockIdx.x, h = blockIdx.y;
    if (x >= NL) return;
    u16* Vt = reinterpret_cast<u16*>(ldsraw);                              // [32][200]
    float* Ob = reinterpret_cast<float*>(ldsraw + 12800) + (size_t)w * 416; // [16][26]
    int l = lp0 + x;
    int lrel = x;
    const bf16* vs = &vbuf[((size_t)l * 12 + h) * 4608];
    for (int u = t; u < 576; u += 256) {
      int kk = u / 3, c0 = (u % 3) * 8;
      uint4 val = *reinterpret_cast<const uint4*>(&vs[kk * 24 + c0]);
      const u16* pv = reinterpret_cast<const u16*>(&val);
#pragma unroll
      for (int i = 0; i < 8; ++i) Vt[(c0 + i) * 200 + kk] = pv[i];
    }
    __syncthreads();
    bf16x8 bfr[6][2];
#pragma unroll
    for (int kt = 0; kt < 6; ++kt)
#pragma unroll
      for (int nt = 0; nt < 2; ++nt)
        bfr[kt][nt] = *reinterpret_cast<const bf16x8*>(
            &Vt[(nt * 16 + c15) * 200 + kt * 32 + g * 8]);
    const bf16* Ps = &Ppv[((size_t)lrel * 12 + h) * 36864];
#pragma unroll
    for (int mi = 0; mi < 3; ++mi) {
      int mt = w * 3 + mi;
      f32x4 acc0 = (f32x4){0.f, 0.f, 0.f, 0.f};
      f32x4 acc1 = (f32x4){0.f, 0.f, 0.f, 0.f};
#pragma unroll
      for (int kt = 0; kt < 6; ++kt) {
        bf16x8 a = *reinterpret_cast<const bf16x8*>(
            &Ps[(size_t)(mt * 16 + c15) * 192 + kt * 32 + g * 8]);
        acc0 = __builtin_amdgcn_mfma_f32_16x16x32_bf16(a, bfr[kt][0], acc0, 0, 0, 0);
        acc1 = __builtin_amdgcn_mfma_f32_16x16x32_bf16(a, bfr[kt][1], acc1, 0, 0, 0);
      }
#pragma unroll
      for (int i = 0; i < 4; ++i) {
        Ob[(4 * g + i) * 26 + c15] = acc0[i];
        if (c15 < 8) Ob[(4 * g + i) * 26 + 16 + c15] = acc1[i];
      }
      if (lane < 48) {
        int r = lane / 3, c0 = (lane % 3) * 8;
        int b = mt * 16 + r;
        size_t m = (size_t)b * 192 + l;
        uint4 gv4 = *reinterpret_cast<const uint4*>(&gbuf[m * 288 + h * 24 + c0]);
        const u16* gp = reinterpret_cast<const u16*>(&gv4);
        u16 opk[8];
#pragma unroll
        for (int i = 0; i < 8; ++i) {
          float av = Ob[r * 26 + c0 + i];
          float sg = 1.0f / (1.0f + __expf(-bf2f(gp[i])));
          opk[i] = f2bf(av * sg);
        }
        *reinterpret_cast<uint4*>(&ogb[m * 288 + h * 24 + c0]) = *reinterpret_cast<uint4*>(opk);
      }
    }
  }
}

// ---------------- kernel 5: out = ogb @ Wo + bo (MFMA, M-tile 64) ----------------
__global__ __launch_bounds__(256) void k_out(const bf16* __restrict__ ogb,
                                             const bf16* __restrict__ Wot,
                                             const float* __restrict__ bo,
                                             float* __restrict__ out) {
  int t = threadIdx.x;
  int w = t >> 6, lane = t & 63;
  int c15 = lane & 15, g = lane >> 4;
  int m0 = blockIdx.x * 64;
  int mrow = m0 + w * 16 + c15;
  f32x4 acc[8];
#pragma unroll
  for (int nt = 0; nt < 8; ++nt) acc[nt] = (f32x4){0.f, 0.f, 0.f, 0.f};
#pragma unroll
  for (int kt = 0; kt < 9; ++kt) {
    bf16x8 a = *reinterpret_cast<const bf16x8*>(&ogb[(size_t)mrow * 288 + kt * 32 + g * 8]);
    bf16x8 b[8];
#pragma unroll
    for (int nt = 0; nt < 8; ++nt)
      b[nt] = *reinterpret_cast<const bf16x8*>(&Wot[(size_t)(nt * 16 + c15) * 288 + kt * 32 + g * 8]);
#pragma unroll
    for (int nt = 0; nt < 8; ++nt)
      acc[nt] = __builtin_amdgcn_mfma_f32_16x16x32_bf16(a, b[nt], acc[nt], 0, 0, 0);
  }
#pragma unroll
  for (int nt = 0; nt < 8; ++nt) {
    int n = nt * 16 + c15;
    float bval = bo[n];
#pragma unroll
    for (int i = 0; i < 4; ++i) {
      int m = m0 + w * 16 + 4 * g + i;
      out[(size_t)m * 128 + n] = acc[nt][i] + bval;
    }
  }
}

extern "C" void kernel_launch(void* const* d_in, const int* in_sizes, int n_in,
                              void* d_out, int out_size, void* d_ws, size_t ws_size,
                              hipStream_t stream) {
  const float* z_in = (const float*)d_in[0];
  const float* ln_w = (const float*)d_in[1];
  const float* ln_b = (const float*)d_in[2];
  const float* Wq   = (const float*)d_in[3];
  const float* bq   = (const float*)d_in[4];
  const float* Wk   = (const float*)d_in[5];
  const float* bk   = (const float*)d_in[6];
  const float* Wv   = (const float*)d_in[7];
  const float* bv   = (const float*)d_in[8];
  const float* Wb   = (const float*)d_in[9];
  const float* bb   = (const float*)d_in[10];
  const float* Wg   = (const float*)d_in[11];
  const float* bg   = (const float*)d_in[12];
  const float* Wo   = (const float*)d_in[13];
  const float* bo   = (const float*)d_in[14];
  float* out = (float*)d_out;

  char* ws = (char*)d_ws;
  // layout (fallback-compatible; ogb separate from q2 -> overlap-safe)
  bf16* q2    = (bf16*)(ws + 0);            // [b][h][l][24]
  bf16* k2    = (bf16*)(ws + 21233664);     // [b][h][kk][24]
  bf16* vb    = (bf16*)(ws + 42467328);     // [l][h][kk][24]
  bf16* gbuf  = (bf16*)(ws + 63700992);     // [m][288]
  bf16* ogb   = (bf16*)(ws + 84934656);     // [m][288]
  bf16* zb    = (bf16*)(ws + 84934656);     // union: dead after k_proj
  bf16* Wcat  = (bf16*)(ws + 94371840);     // union in ogb: dead after k_proj
  float* biasb = (float*)(ws + 106168320);  // [12][192][192] f32 (transposed-in-16)
  char* Pbase = ws + 107937792;
  bf16* Wot   = (bf16*)(ws + 107937792);    // union with P (written after pv loop)
  const size_t PB = 107937792ull;

  k_cvt<<<dim3(72), dim3(256), 0, stream>>>(Wq, Wk, Wv, Wg, Wcat);
  k_ln<<<dim3(9216), dim3(256), 0, stream>>>(z_in, ln_w, ln_b, zb);
  k_bias<<<dim3(576), dim3(256), 0, stream>>>(zb, Wb, bb, biasb);
  k_proj<<<dim3(192, 12), dim3(256), 0, stream>>>(zb, Wcat, bq, bk, bv, bg,
                                                  q2, k2, vb, gbuf);

  if (ws_size >= PB + 113246208ull) {
    // ---- CL=64 software pipeline: att(n+1) overlaps pv(n) ----
    bf16* P0 = (bf16*)Pbase;                       // 56,623,104 B each
    bf16* P1 = (bf16*)(Pbase + 56623104);
    // d1: att rows 0..63 -> P0 (z-split: ZA=2, NT=2)
    k_attpv<<<dim3(48, 12, 2), dim3(256), 0, stream>>>(
        q2, k2, biasb, vb, gbuf, P0, P0, ogb, 0, -1, 2, 0, 2);
    // d2: att 64..127 -> P1  ||  pv 0..63 <- P0
    k_attpv<<<dim3(64, 12, 3), dim3(256), 0, stream>>>(
        q2, k2, biasb, vb, gbuf, P1, P0, ogb, 64, 0, 2, 64, 2);
    // d3: att 128..191 -> P0  ||  pv 64..127 <- P1
    k_attpv<<<dim3(64, 12, 3), dim3(256), 0, stream>>>(
        q2, k2, biasb, vb, gbuf, P0, P1, ogb, 128, 64, 2, 64, 2);
    // d4: pv 128..191 <- P0
    k_attpv<<<dim3(64, 12, 1), dim3(256), 0, stream>>>(
        q2, k2, biasb, vb, gbuf, P0, P0, ogb, -1, 128, 0, 64, 0);
  } else {
    int CL;
    if      (ws_size >= PB + 84934656ull)  CL = 48;   // dbuf 48
    else if (ws_size >= PB + 56623104ull)  CL = 32;   // dbuf 32
    else if (ws_size >= PB + 28311552ull)  CL = 16;   // dbuf 16
    else                                   CL = -16;  // serial 16, single buffer
    if (CL > 0) {
      int nch = 192 / CL;
      size_t csz = (size_t)CL * 884736ull;
      bf16* P0 = (bf16*)Pbase;
      bf16* P1 = (bf16*)(Pbase + csz);
      int NT = CL / 16;
      for (int n = 0; n <= nch; ++n) {
        bf16* Pa = (n & 1) ? P1 : P0;
        bf16* Pp = ((n - 1) & 1) ? P1 : P0;
        int la = (n < nch) ? n * CL : -1;
        int lp = (n >= 1) ? (n - 1) * CL : -1;
        if (la >= 0 && lp >= 0)
          k_attpv<<<dim3(48 > CL ? 48 : CL, 12, 2), dim3(256), 0, stream>>>(
              q2, k2, biasb, vb, gbuf, Pa, Pp, ogb, la, lp, NT, CL, 1);
        else if (la >= 0)
          k_attpv<<<dim3(48, 12, 1), dim3(256), 0, stream>>>(
              q2, k2, biasb, vb, gbuf, Pa, Pp, ogb, la, -1, NT, CL, 1);
        else
          k_attpv<<<dim3(CL, 12, 1), dim3(256), 0, stream>>>(
              q2, k2, biasb, vb, gbuf, Pa, Pp, ogb, -1, lp, NT, CL, 0);
      }
    } else {
      bf16* P0 = (bf16*)Pbase;
      for (int n = 0; n < 12; ++n) {
        k_attpv<<<dim3(48, 12, 1), dim3(256), 0, stream>>>(
            q2, k2, biasb, vb, gbuf, P0, P0, ogb, n * 16, -1, 1, 16, 1);
        k_attpv<<<dim3(16, 12, 1), dim3(256), 0, stream>>>(
            q2, k2, biasb, vb, gbuf, P0, P0, ogb, -1, n * 16, 1, 16, 0);
      }
    }
  }
  k_cvt2<<<dim3(18), dim3(256), 0, stream>>>(Wo, Wot);
  k_out<<<dim3(576), dim3(256), 0, stream>>>(ogb, Wot, bo, out);
}

// Round 20
// 227.032 us; speedup vs baseline: 1.0548x; 1.0548x over previous
//
#include <hip/hip_runtime.h>
#include <hip/hip_bf16.h>
#include <math.h>

typedef __hip_bfloat16 bf16;
typedef unsigned short u16;
typedef unsigned int u32;
typedef __attribute__((ext_vector_type(8))) short bf16x8;
typedef __attribute__((ext_vector_type(4))) float f32x4;

#define LL 36864  // L*L

__device__ __forceinline__ float wave_sum(float v) {
#pragma unroll
  for (int m = 32; m; m >>= 1) v += __shfl_xor(v, m, 64);
  return v;
}

__device__ __forceinline__ float bf2f(u16 u) {
  union { float f; u32 u; } c; c.u = ((u32)u) << 16; return c.f;
}
__device__ __forceinline__ u16 f2bf(float f) {  // RNE
  union { float f; u32 u; } c; c.f = f;
  u32 r = c.u + 0x7fffu + ((c.u >> 16) & 1u);
  return (u16)(r >> 16);
}

// ---------------- kernel 0a: Wq|Wk|Wv|Wg -> Wcat[jg][128] bf16 ----------------
__global__ __launch_bounds__(256) void k_cvt(const float* __restrict__ Wq,
                                             const float* __restrict__ Wk,
                                             const float* __restrict__ Wv,
                                             const float* __restrict__ Wg,
                                             bf16* __restrict__ Wcat) {
  int u = blockIdx.x * 256 + threadIdx.x;   // 18432 tasks
  if (u >= 18432) return;
  int jg = u >> 4, k0 = (u & 15) * 8;
  int sec = jg / 288, j = jg % 288;
  const float* W = sec == 0 ? Wq : sec == 1 ? Wk : sec == 2 ? Wv : Wg;
  u16 pk[8];
#pragma unroll
  for (int i = 0; i < 8; ++i) pk[i] = f2bf(W[(size_t)(k0 + i) * 288 + j]);
  *reinterpret_cast<uint4*>(&Wcat[(size_t)jg * 128 + k0]) = *reinterpret_cast<uint4*>(pk);
}

// ---------------- kernel 0b: Wo -> Wot[n][288] bf16 ----------------
__global__ __launch_bounds__(256) void k_cvt2(const float* __restrict__ Wo,
                                              bf16* __restrict__ Wot) {
  int u = blockIdx.x * 256 + threadIdx.x;   // 4608 tasks
  if (u >= 4608) return;
  int n = u / 36, k0 = (u % 36) * 8;
  u16 pk[8];
#pragma unroll
  for (int i = 0; i < 8; ++i) pk[i] = f2bf(Wo[(size_t)(k0 + i) * 128 + n]);
  *reinterpret_cast<uint4*>(&Wot[(size_t)n * 288 + k0]) = *reinterpret_cast<uint4*>(pk);
}

// ---------------- kernel 1: LayerNorm (pure) ----------------
__global__ __launch_bounds__(256) void k_ln(const float* __restrict__ zin,
                                            const float* __restrict__ w_,
                                            const float* __restrict__ b_,
                                            bf16* __restrict__ zb) {
  int t = threadIdx.x;
  int wv = t >> 6, lane = t & 63;
  size_t m = (size_t)blockIdx.x * 4 + wv;
  const float2 v = *reinterpret_cast<const float2*>(&zin[m * 128 + lane * 2]);
  float s = wave_sum(v.x + v.y);
  float ss = wave_sum(v.x * v.x + v.y * v.y);
  float mean = s * (1.0f / 128.0f);
  float var = ss * (1.0f / 128.0f) - mean * mean;
  float rs = rsqrtf(var + 1e-5f);
  float o0 = (v.x - mean) * rs * w_[lane * 2] + b_[lane * 2];
  float o1 = (v.y - mean) * rs * w_[lane * 2 + 1] + b_[lane * 2 + 1];
  u32 pk = (u32)f2bf(o0) | ((u32)f2bf(o1) << 16);
  *reinterpret_cast<u32*>(&zb[m * 128 + lane * 2]) = pk;
}

// ---------------- kernel 1b: bias projection via MFMA ----------------
// biasT[h][l][(kk&15)*12 + (kk>>4)] = (zb @ Wb)[m= kk*192+l][h] + bb[h]
// wave handles 16 consecutive m-rows (one kk); 4 MFMAs over K=128
__global__ __launch_bounds__(256) void k_bias(const bf16* __restrict__ zb,
                                              const float* __restrict__ Wb,
                                              const float* __restrict__ bbv,
                                              float* __restrict__ biasb) {
  int t = threadIdx.x;
  int w = t >> 6, lane = t & 63;
  int c15 = lane & 15, g = lane >> 4;
  int m0 = (blockIdx.x * 4 + w) * 16;
  f32x4 acc = (f32x4){0.f, 0.f, 0.f, 0.f};
#pragma unroll
  for (int kt = 0; kt < 4; ++kt) {
    bf16x8 a = *reinterpret_cast<const bf16x8*>(
        &zb[(size_t)(m0 + c15) * 128 + kt * 32 + g * 8]);
    u16 bp[8];
#pragma unroll
    for (int j = 0; j < 8; ++j)
      bp[j] = (c15 < 12) ? f2bf(Wb[(size_t)(kt * 32 + g * 8 + j) * 12 + c15]) : (u16)0;
    bf16x8 b = *reinterpret_cast<bf16x8*>(bp);
    acc = __builtin_amdgcn_mfma_f32_16x16x32_bf16(a, b, acc, 0, 0, 0);
  }
  if (c15 < 12) {
    int kk = m0 / 192, l0 = m0 % 192;
    int p = (kk & 15) * 12 + (kk >> 4);
    float bv = bbv[c15];
#pragma unroll
    for (int i = 0; i < 4; ++i) {
      int l = l0 + 4 * g + i;
      biasb[(size_t)c15 * LL + (size_t)l * 192 + p] = acc[i] + bv;
    }
  }
}

// ---------------- kernel 2: projections (MFMA, 192x96 tiles, LDS-bounced stores) ----
__global__ __launch_bounds__(256) void k_proj(const bf16* __restrict__ zb,
    const bf16* __restrict__ Wcat,
    const float* __restrict__ bq, const float* __restrict__ bk,
    const float* __restrict__ bv, const float* __restrict__ bg,
    bf16* __restrict__ q2, bf16* __restrict__ k2,
    bf16* __restrict__ vb, bf16* __restrict__ gbuf) {
  __shared__ __align__(16) u16 Sb[192 * 104];
  int t = threadIdx.x;
  int w = t >> 6, lane = t & 63;
  int c15 = lane & 15, g = lane >> 4;
  int wm = w & 1, wn = w >> 1;
  int bx = blockIdx.x, y = blockIdx.y;
  int sec = y / 3, h0 = (y % 3) * 4;
  int m0 = bx * 192;
  int jbase = y * 96;
  f32x4 acc[6][3];
#pragma unroll
  for (int mt = 0; mt < 6; ++mt)
#pragma unroll
    for (int nt = 0; nt < 3; ++nt) acc[mt][nt] = (f32x4){0.f, 0.f, 0.f, 0.f};
#pragma unroll
  for (int kt = 0; kt < 4; ++kt) {
    bf16x8 a[6], b[3];
#pragma unroll
    for (int mt = 0; mt < 6; ++mt)
      a[mt] = *reinterpret_cast<const bf16x8*>(
          &zb[(size_t)(m0 + wm * 96 + mt * 16 + c15) * 128 + kt * 32 + g * 8]);
#pragma unroll
    for (int nt = 0; nt < 3; ++nt)
      b[nt] = *reinterpret_cast<const bf16x8*>(
          &Wcat[(size_t)(jbase + wn * 48 + nt * 16 + c15) * 128 + kt * 32 + g * 8]);
#pragma unroll
    for (int mt = 0; mt < 6; ++mt)
#pragma unroll
      for (int nt = 0; nt < 3; ++nt)
        acc[mt][nt] = __builtin_amdgcn_mfma_f32_16x16x32_bf16(a[mt], b[nt], acc[mt][nt], 0, 0, 0);
  }
  const float* barr = sec == 0 ? bq : sec == 1 ? bk : sec == 2 ? bv : bg;
#pragma unroll
  for (int nt = 0; nt < 3; ++nt) {
    int col = wn * 48 + nt * 16 + c15;
    float bval = barr[(y % 3) * 96 + col];
#pragma unroll
    for (int mt = 0; mt < 6; ++mt) {
      int rbase = wm * 96 + mt * 16 + 4 * g;
#pragma unroll
      for (int i = 0; i < 4; ++i)
        Sb[(rbase + i) * 104 + col] = f2bf(acc[mt][nt][i] + bval);
    }
  }
  __syncthreads();
  if (sec == 0) {
    bf16* dst0 = q2 + ((size_t)bx * 12 + h0) * 4608;
    for (int u = t; u < 2304; u += 256) {
      int hl = u / 576, off = (u % 576) * 8;
      int ml = off / 24, c0 = off % 24;
      uint4 val = *reinterpret_cast<const uint4*>(&Sb[ml * 104 + hl * 24 + c0]);
      *reinterpret_cast<uint4*>(&dst0[(size_t)hl * 4608 + off]) = val;
    }
  } else if (sec == 3) {
    for (int u = t; u < 2304; u += 256) {
      int ml = u / 12, col = (u % 12) * 8;
      uint4 val = *reinterpret_cast<const uint4*>(&Sb[ml * 104 + col]);
      *reinterpret_cast<uint4*>(&gbuf[(size_t)(m0 + ml) * 288 + h0 * 24 + col]) = val;
    }
  } else {
    bf16* dst = (sec == 1) ? k2 : vb;
    for (int u = t; u < 2304; u += 256) {
      int hl = u / 576, off = (u % 576) * 8;
      int ml = off / 24, c0 = off % 24;
      uint4 val = *reinterpret_cast<const uint4*>(&Sb[ml * 104 + hl * 24 + c0]);
      *reinterpret_cast<uint4*>(
          &dst[(((size_t)ml * 12 + h0 + hl) * 192 + bx) * 24 + c0]) = val;
    }
  }
}

// ---------------- kernel 3: attention, role-switched ----------------
// att role (la0>=0 and (lp0<0 or z==0)): wave=(bq,h); block z handles NT l-tiles
//   bias via transposed layout: lane c15 reads 12 contiguous floats (3x float4)
// pv role: block=(x -> l = lp0+x, h): 4 waves split 192 b-rows; Ob bounce; gated store
__global__ __launch_bounds__(256) void k_attpv(const bf16* __restrict__ q2,
    const bf16* __restrict__ k2, const float* __restrict__ biasb,
    const bf16* __restrict__ vbuf, const bf16* __restrict__ gbuf,
    bf16* __restrict__ Patt, const bf16* __restrict__ Ppv,
    bf16* __restrict__ ogb, int la0, int lp0, int NT, int NL) {
  __shared__ __align__(16) char ldsraw[25600];
  int t = threadIdx.x;
  int w = t >> 6, lane = t & 63;
  int c15 = lane & 15, g = lane >> 4;
  const float sq_c = 0.20412414523193154f;  // 1/sqrt(24)
  bool is_att = (la0 >= 0) && (lp0 < 0 || blockIdx.z == 0);
  if (is_att) {
    int x = blockIdx.x, h = blockIdx.y;
    if (x >= 48) return;
    int bq = x * 4 + w;
    int lbase = la0 + blockIdx.z * NT * 16;
    u16* Sb = reinterpret_cast<u16*>(ldsraw) + (size_t)w * 3200;  // per-wave [16][200]
    const bf16* ks = &k2[((size_t)bq * 12 + h) * 4608];
    const float* bsrc = &biasb[(size_t)h * LL];
    for (int lt = 0; lt < NT; ++lt) {
      int l0 = lbase + lt * 16;
      const bf16* qs = &q2[(((size_t)bq * 12 + h) * 192 + l0) * 24];
      bf16x8 afr = {0, 0, 0, 0, 0, 0, 0, 0};
      if (g < 3) afr = *reinterpret_cast<const bf16x8*>(&qs[c15 * 24 + g * 8]);
      f32x4 acc[12];
#pragma unroll
      for (int ct = 0; ct < 12; ++ct) {
        bf16x8 bfr = {0, 0, 0, 0, 0, 0, 0, 0};
        if (g < 3) bfr = *reinterpret_cast<const bf16x8*>(&ks[(ct * 16 + c15) * 24 + g * 8]);
        acc[ct] = __builtin_amdgcn_mfma_f32_16x16x32_bf16(afr, bfr, (f32x4){0.f, 0.f, 0.f, 0.f}, 0, 0, 0);
      }
      // bias: lane c15 reads 12 contiguous floats per row (transposed layout)
#pragma unroll
      for (int i = 0; i < 4; ++i) {
        const float* bT = &bsrc[(size_t)(l0 + 4 * g + i) * 192 + c15 * 12];
        float4 b0 = *reinterpret_cast<const float4*>(&bT[0]);
        float4 b1 = *reinterpret_cast<const float4*>(&bT[4]);
        float4 b2 = *reinterpret_cast<const float4*>(&bT[8]);
        float bb12[12] = {b0.x, b0.y, b0.z, b0.w, b1.x, b1.y, b1.z, b1.w,
                          b2.x, b2.y, b2.z, b2.w};
#pragma unroll
        for (int ct = 0; ct < 12; ++ct)
          acc[ct][i] = acc[ct][i] * sq_c + bb12[ct];
      }
      float inv[4];
#pragma unroll
      for (int i = 0; i < 4; ++i) {
        float mx = -1e30f;
#pragma unroll
        for (int ct = 0; ct < 12; ++ct) mx = fmaxf(mx, acc[ct][i]);
#pragma unroll
        for (int msk = 1; msk < 16; msk <<= 1) mx = fmaxf(mx, __shfl_xor(mx, msk, 64));
        float sm = 0.f;
#pragma unroll
        for (int ct = 0; ct < 12; ++ct) {
          float e = __expf(acc[ct][i] - mx);
          acc[ct][i] = e;
          sm += e;
        }
#pragma unroll
        for (int msk = 1; msk < 16; msk <<= 1) sm += __shfl_xor(sm, msk, 64);
        inv[i] = 1.0f / sm;
      }
#pragma unroll
      for (int i = 0; i < 4; ++i)
#pragma unroll
        for (int ct = 0; ct < 12; ++ct)
          Sb[(4 * g + i) * 200 + ct * 16 + c15] = f2bf(acc[ct][i] * inv[i]);
      int lrel = l0 - la0;
      for (int u = lane; u < 384; u += 64) {
        int lloc = u / 24, oct = u % 24;
        uint4 val = *reinterpret_cast<const uint4*>(&Sb[lloc * 200 + oct * 8]);
        *reinterpret_cast<uint4*>(
            &Patt[(((size_t)(lrel + lloc) * 12 + h) * 192 + bq) * 192 + oct * 8]) = val;
      }
    }
  } else {
    if (lp0 < 0) return;
    int x = blockIdx.x, h = blockIdx.y;
    if (x >= NL) return;
    u16* Vt = reinterpret_cast<u16*>(ldsraw);                              // [32][200]
    float* Ob = reinterpret_cast<float*>(ldsraw + 12800) + (size_t)w * 416; // [16][26]
    int l = lp0 + x;
    int lrel = x;
    const bf16* vs = &vbuf[((size_t)l * 12 + h) * 4608];
    for (int u = t; u < 576; u += 256) {
      int kk = u / 3, c0 = (u % 3) * 8;
      uint4 val = *reinterpret_cast<const uint4*>(&vs[kk * 24 + c0]);
      const u16* pv = reinterpret_cast<const u16*>(&val);
#pragma unroll
      for (int i = 0; i < 8; ++i) Vt[(c0 + i) * 200 + kk] = pv[i];
    }
    __syncthreads();
    bf16x8 bfr[6][2];
#pragma unroll
    for (int kt = 0; kt < 6; ++kt)
#pragma unroll
      for (int nt = 0; nt < 2; ++nt)
        bfr[kt][nt] = *reinterpret_cast<const bf16x8*>(
            &Vt[(nt * 16 + c15) * 200 + kt * 32 + g * 8]);
    const bf16* Ps = &Ppv[((size_t)lrel * 12 + h) * 36864];
#pragma unroll
    for (int mi = 0; mi < 3; ++mi) {
      int mt = w * 3 + mi;
      f32x4 acc0 = (f32x4){0.f, 0.f, 0.f, 0.f};
      f32x4 acc1 = (f32x4){0.f, 0.f, 0.f, 0.f};
#pragma unroll
      for (int kt = 0; kt < 6; ++kt) {
        bf16x8 a = *reinterpret_cast<const bf16x8*>(
            &Ps[(size_t)(mt * 16 + c15) * 192 + kt * 32 + g * 8]);
        acc0 = __builtin_amdgcn_mfma_f32_16x16x32_bf16(a, bfr[kt][0], acc0, 0, 0, 0);
        acc1 = __builtin_amdgcn_mfma_f32_16x16x32_bf16(a, bfr[kt][1], acc1, 0, 0, 0);
      }
#pragma unroll
      for (int i = 0; i < 4; ++i) {
        Ob[(4 * g + i) * 26 + c15] = acc0[i];
        if (c15 < 8) Ob[(4 * g + i) * 26 + 16 + c15] = acc1[i];
      }
      if (lane < 48) {
        int r = lane / 3, c0 = (lane % 3) * 8;
        int b = mt * 16 + r;
        size_t m = (size_t)b * 192 + l;
        uint4 gv4 = *reinterpret_cast<const uint4*>(&gbuf[m * 288 + h * 24 + c0]);
        const u16* gp = reinterpret_cast<const u16*>(&gv4);
        u16 opk[8];
#pragma unroll
        for (int i = 0; i < 8; ++i) {
          float av = Ob[r * 26 + c0 + i];
          float sg = 1.0f / (1.0f + __expf(-bf2f(gp[i])));
          opk[i] = f2bf(av * sg);
        }
        *reinterpret_cast<uint4*>(&ogb[m * 288 + h * 24 + c0]) = *reinterpret_cast<uint4*>(opk);
      }
    }
  }
}

// ---------------- kernel 5: out = ogb @ Wo + bo (MFMA, M-tile 64) ----------------
__global__ __launch_bounds__(256) void k_out(const bf16* __restrict__ ogb,
                                             const bf16* __restrict__ Wot,
                                             const float* __restrict__ bo,
                                             float* __restrict__ out) {
  int t = threadIdx.x;
  int w = t >> 6, lane = t & 63;
  int c15 = lane & 15, g = lane >> 4;
  int m0 = blockIdx.x * 64;
  int mrow = m0 + w * 16 + c15;
  f32x4 acc[8];
#pragma unroll
  for (int nt = 0; nt < 8; ++nt) acc[nt] = (f32x4){0.f, 0.f, 0.f, 0.f};
#pragma unroll
  for (int kt = 0; kt < 9; ++kt) {
    bf16x8 a = *reinterpret_cast<const bf16x8*>(&ogb[(size_t)mrow * 288 + kt * 32 + g * 8]);
    bf16x8 b[8];
#pragma unroll
    for (int nt = 0; nt < 8; ++nt)
      b[nt] = *reinterpret_cast<const bf16x8*>(&Wot[(size_t)(nt * 16 + c15) * 288 + kt * 32 + g * 8]);
#pragma unroll
    for (int nt = 0; nt < 8; ++nt)
      acc[nt] = __builtin_amdgcn_mfma_f32_16x16x32_bf16(a, b[nt], acc[nt], 0, 0, 0);
  }
#pragma unroll
  for (int nt = 0; nt < 8; ++nt) {
    int n = nt * 16 + c15;
    float bval = bo[n];
#pragma unroll
    for (int i = 0; i < 4; ++i) {
      int m = m0 + w * 16 + 4 * g + i;
      out[(size_t)m * 128 + n] = acc[nt][i] + bval;
    }
  }
}

extern "C" void kernel_launch(void* const* d_in, const int* in_sizes, int n_in,
                              void* d_out, int out_size, void* d_ws, size_t ws_size,
                              hipStream_t stream) {
  const float* z_in = (const float*)d_in[0];
  const float* ln_w = (const float*)d_in[1];
  const float* ln_b = (const float*)d_in[2];
  const float* Wq   = (const float*)d_in[3];
  const float* bq   = (const float*)d_in[4];
  const float* Wk   = (const float*)d_in[5];
  const float* bk   = (const float*)d_in[6];
  const float* Wv   = (const float*)d_in[7];
  const float* bv   = (const float*)d_in[8];
  const float* Wb   = (const float*)d_in[9];
  const float* bb   = (const float*)d_in[10];
  const float* Wg   = (const float*)d_in[11];
  const float* bg   = (const float*)d_in[12];
  const float* Wo   = (const float*)d_in[13];
  const float* bo   = (const float*)d_in[14];
  float* out = (float*)d_out;

  char* ws = (char*)d_ws;

  if (ws_size >= 256573440ull) {
    // ---- full-P compact plan ----
    bf16* q2    = (bf16*)(ws + 0);            // [b][h][l][24]; ogb aliases after att
    bf16* ogb   = (bf16*)(ws + 0);
    bf16* k2    = (bf16*)(ws + 21233664);     // [b][h][kk][24]
    bf16* vb    = (bf16*)(ws + 42467328);     // [l][h][kk][24]
    bf16* gbuf  = (bf16*)(ws + 63700992);     // [m][288]
    float* biasb = (float*)(ws + 84934656);   // [12][192][192] f32 (transposed-in-16)
    bf16* P     = (bf16*)(ws + 86704128);     // [l][h][b][kk] full
    bf16* zb    = (bf16*)(ws + 86704128);     // union in P: dead after k_proj
    bf16* Wcat  = (bf16*)(ws + 96141312);     // union in P: dead after k_proj
    bf16* Wot   = (bf16*)(ws + 86704128);     // union in P: written after pv

    k_cvt<<<dim3(72), dim3(256), 0, stream>>>(Wq, Wk, Wv, Wg, Wcat);
    k_ln<<<dim3(9216), dim3(256), 0, stream>>>(z_in, ln_w, ln_b, zb);
    k_bias<<<dim3(576), dim3(256), 0, stream>>>(zb, Wb, bb, biasb);
    k_proj<<<dim3(192, 12), dim3(256), 0, stream>>>(zb, Wcat, bq, bk, bv, bg,
                                                    q2, k2, vb, gbuf);
    // att split over z: 4 z-slices x 3 l-tiles each -> 2304 blocks
    k_attpv<<<dim3(48, 12, 4), dim3(256), 0, stream>>>(
        q2, k2, biasb, vb, gbuf, P, P, ogb, 0, -1, 3, 192);
    k_attpv<<<dim3(192, 12, 1), dim3(256), 0, stream>>>(
        q2, k2, biasb, vb, gbuf, P, P, ogb, -1, 0, 12, 192);
    k_cvt2<<<dim3(18), dim3(256), 0, stream>>>(Wo, Wot);
    k_out<<<dim3(576), dim3(256), 0, stream>>>(ogb, Wot, bo, out);
    return;
  }

  // ---- fallback: round-10 proven layout & ladder ----
  bf16* q2    = (bf16*)(ws + 0);            // [b][h][l][24]
  bf16* k2    = (bf16*)(ws + 21233664);     // [b][h][kk][24]
  bf16* vb    = (bf16*)(ws + 42467328);     // [l][h][kk][24]
  bf16* gbuf  = (bf16*)(ws + 63700992);     // [m][288]
  bf16* ogb   = (bf16*)(ws + 84934656);     // [m][288]
  bf16* zb    = (bf16*)(ws + 84934656);     // union: dead after k_proj
  bf16* Wcat  = (bf16*)(ws + 94371840);     // union in ogb: dead after k_proj
  float* biasb = (float*)(ws + 106168320);  // [12][192][192] f32
  char* Pbase = ws + 107937792;
  bf16* Wot   = (bf16*)(ws + 107937792);    // union with P (written after pv loop)

  k_cvt<<<dim3(72), dim3(256), 0, stream>>>(Wq, Wk, Wv, Wg, Wcat);
  k_ln<<<dim3(9216), dim3(256), 0, stream>>>(z_in, ln_w, ln_b, zb);
  k_bias<<<dim3(576), dim3(256), 0, stream>>>(zb, Wb, bb, biasb);
  k_proj<<<dim3(192, 12), dim3(256), 0, stream>>>(zb, Wcat, bq, bk, bv, bg,
                                                  q2, k2, vb, gbuf);
  const size_t PB = 107937792ull;
  int CL;
  if      (ws_size >= PB + 84934656ull)  CL = 48;   // dbuf 48
  else if (ws_size >= PB + 56623104ull)  CL = 32;   // dbuf 32
  else if (ws_size >= PB + 28311552ull)  CL = 16;   // dbuf 16
  else                                   CL = -16;  // serial 16, single buffer
  if (CL > 0) {
    int nch = 192 / CL;
    size_t csz = (size_t)CL * 884736ull;  // CL*12*192*192*2 bytes
    bf16* P0 = (bf16*)Pbase;
    bf16* P1 = (bf16*)(Pbase + csz);
    int NT = CL / 16;
    for (int n = 0; n <= nch; ++n) {
      bf16* Pa = (n & 1) ? P1 : P0;
      bf16* Pp = ((n - 1) & 1) ? P1 : P0;
      int la = (n < nch) ? n * CL : -1;
      int lp = (n >= 1) ? (n - 1) * CL : -1;
      if (la >= 0 && lp >= 0)
        k_attpv<<<dim3(48 > CL ? 48 : CL, 12, 2), dim3(256), 0, stream>>>(
            q2, k2, biasb, vb, gbuf, Pa, Pp, ogb, la, lp, NT, CL);
      else if (la >= 0)
        k_attpv<<<dim3(48, 12, 1), dim3(256), 0, stream>>>(
            q2, k2, biasb, vb, gbuf, Pa, Pp, ogb, la, -1, NT, CL);
      else
        k_attpv<<<dim3(CL, 12, 1), dim3(256), 0, stream>>>(
            q2, k2, biasb, vb, gbuf, Pa, Pp, ogb, -1, lp, NT, CL);
    }
  } else {
    bf16* P0 = (bf16*)Pbase;
    for (int n = 0; n < 12; ++n) {
      k_attpv<<<dim3(48, 12, 1), dim3(256), 0, stream>>>(
          q2, k2, biasb, vb, gbuf, P0, P0, ogb, n * 16, -1, 1, 16);
      k_attpv<<<dim3(16, 12, 1), dim3(256), 0, stream>>>(
          q2, k2, biasb, vb, gbuf, P0, P0, ogb, -1, n * 16, 1, 16);
    }
  }
  k_cvt2<<<dim3(18), dim3(256), 0, stream>>>(Wo, Wot);
  k_out<<<dim3(576), dim3(256), 0, stream>>>(ogb, Wot, bo, out);
}

// Round 21
// 222.762 us; speedup vs baseline: 1.0750x; 1.0192x over previous
//
#include <hip/hip_runtime.h>
#include <hip/hip_bf16.h>
#include <math.h>

typedef __hip_bfloat16 bf16;
typedef unsigned short u16;
typedef unsigned int u32;
typedef __attribute__((ext_vector_type(8))) short bf16x8;
typedef __attribute__((ext_vector_type(4))) float f32x4;

#define LL 36864  // L*L

__device__ __forceinline__ float wave_sum(float v) {
#pragma unroll
  for (int m = 32; m; m >>= 1) v += __shfl_xor(v, m, 64);
  return v;
}

__device__ __forceinline__ float bf2f(u16 u) {
  union { float f; u32 u; } c; c.u = ((u32)u) << 16; return c.f;
}
__device__ __forceinline__ u16 f2bf(float f) {  // RNE
  union { float f; u32 u; } c; c.f = f;
  u32 r = c.u + 0x7fffu + ((c.u >> 16) & 1u);
  return (u16)(r >> 16);
}

// ---------------- kernel 0a: Wq|Wk|Wv|Wg -> Wcat[jg][128] bf16 ----------------
__global__ __launch_bounds__(256) void k_cvt(const float* __restrict__ Wq,
                                             const float* __restrict__ Wk,
                                             const float* __restrict__ Wv,
                                             const float* __restrict__ Wg,
                                             bf16* __restrict__ Wcat) {
  int u = blockIdx.x * 256 + threadIdx.x;   // 18432 tasks
  if (u >= 18432) return;
  int jg = u >> 4, k0 = (u & 15) * 8;
  int sec = jg / 288, j = jg % 288;
  const float* W = sec == 0 ? Wq : sec == 1 ? Wk : sec == 2 ? Wv : Wg;
  u16 pk[8];
#pragma unroll
  for (int i = 0; i < 8; ++i) pk[i] = f2bf(W[(size_t)(k0 + i) * 288 + j]);
  *reinterpret_cast<uint4*>(&Wcat[(size_t)jg * 128 + k0]) = *reinterpret_cast<uint4*>(pk);
}

// ---------------- kernel 0b: Wo -> Wot[n][288] bf16 ----------------
__global__ __launch_bounds__(256) void k_cvt2(const float* __restrict__ Wo,
                                              bf16* __restrict__ Wot) {
  int u = blockIdx.x * 256 + threadIdx.x;   // 4608 tasks
  if (u >= 4608) return;
  int n = u / 36, k0 = (u % 36) * 8;
  u16 pk[8];
#pragma unroll
  for (int i = 0; i < 8; ++i) pk[i] = f2bf(Wo[(size_t)(k0 + i) * 128 + n]);
  *reinterpret_cast<uint4*>(&Wot[(size_t)n * 288 + k0]) = *reinterpret_cast<uint4*>(pk);
}

// ---------------- kernel 1: LayerNorm (pure) ----------------
__global__ __launch_bounds__(256) void k_ln(const float* __restrict__ zin,
                                            const float* __restrict__ w_,
                                            const float* __restrict__ b_,
                                            bf16* __restrict__ zb) {
  int t = threadIdx.x;
  int wv = t >> 6, lane = t & 63;
  size_t m = (size_t)blockIdx.x * 4 + wv;
  const float2 v = *reinterpret_cast<const float2*>(&zin[m * 128 + lane * 2]);
  float s = wave_sum(v.x + v.y);
  float ss = wave_sum(v.x * v.x + v.y * v.y);
  float mean = s * (1.0f / 128.0f);
  float var = ss * (1.0f / 128.0f) - mean * mean;
  float rs = rsqrtf(var + 1e-5f);
  float o0 = (v.x - mean) * rs * w_[lane * 2] + b_[lane * 2];
  float o1 = (v.y - mean) * rs * w_[lane * 2 + 1] + b_[lane * 2 + 1];
  u32 pk = (u32)f2bf(o0) | ((u32)f2bf(o1) << 16);
  *reinterpret_cast<u32*>(&zb[m * 128 + lane * 2]) = pk;
}

// ---------------- kernel 1b: bias projection via MFMA ----------------
// biasT[h][l][(kk&15)*12 + (kk>>4)] = (zb @ Wb)[m= kk*192+l][h] + bb[h]
__global__ __launch_bounds__(256) void k_bias(const bf16* __restrict__ zb,
                                              const float* __restrict__ Wb,
                                              const float* __restrict__ bbv,
                                              float* __restrict__ biasb) {
  int t = threadIdx.x;
  int w = t >> 6, lane = t & 63;
  int c15 = lane & 15, g = lane >> 4;
  int m0 = (blockIdx.x * 4 + w) * 16;
  f32x4 acc = (f32x4){0.f, 0.f, 0.f, 0.f};
#pragma unroll
  for (int kt = 0; kt < 4; ++kt) {
    bf16x8 a = *reinterpret_cast<const bf16x8*>(
        &zb[(size_t)(m0 + c15) * 128 + kt * 32 + g * 8]);
    u16 bp[8];
#pragma unroll
    for (int j = 0; j < 8; ++j)
      bp[j] = (c15 < 12) ? f2bf(Wb[(size_t)(kt * 32 + g * 8 + j) * 12 + c15]) : (u16)0;
    bf16x8 b = *reinterpret_cast<bf16x8*>(bp);
    acc = __builtin_amdgcn_mfma_f32_16x16x32_bf16(a, b, acc, 0, 0, 0);
  }
  if (c15 < 12) {
    int kk = m0 / 192, l0 = m0 % 192;
    int p = (kk & 15) * 12 + (kk >> 4);
    float bv = bbv[c15];
#pragma unroll
    for (int i = 0; i < 4; ++i) {
      int l = l0 + 4 * g + i;
      biasb[(size_t)c15 * LL + (size_t)l * 192 + p] = acc[i] + bv;
    }
  }
}

// ---------------- kernel 2: projections (MFMA, 192x96 tiles, LDS-bounced stores) ----
__global__ __launch_bounds__(256) void k_proj(const bf16* __restrict__ zb,
    const bf16* __restrict__ Wcat,
    const float* __restrict__ bq, const float* __restrict__ bk,
    const float* __restrict__ bv, const float* __restrict__ bg,
    bf16* __restrict__ q2, bf16* __restrict__ k2,
    bf16* __restrict__ vb, bf16* __restrict__ gbuf) {
  __shared__ __align__(16) u16 Sb[192 * 104];
  int t = threadIdx.x;
  int w = t >> 6, lane = t & 63;
  int c15 = lane & 15, g = lane >> 4;
  int wm = w & 1, wn = w >> 1;
  int bx = blockIdx.x, y = blockIdx.y;
  int sec = y / 3, h0 = (y % 3) * 4;
  int m0 = bx * 192;
  int jbase = y * 96;
  f32x4 acc[6][3];
#pragma unroll
  for (int mt = 0; mt < 6; ++mt)
#pragma unroll
    for (int nt = 0; nt < 3; ++nt) acc[mt][nt] = (f32x4){0.f, 0.f, 0.f, 0.f};
#pragma unroll
  for (int kt = 0; kt < 4; ++kt) {
    bf16x8 a[6], b[3];
#pragma unroll
    for (int mt = 0; mt < 6; ++mt)
      a[mt] = *reinterpret_cast<const bf16x8*>(
          &zb[(size_t)(m0 + wm * 96 + mt * 16 + c15) * 128 + kt * 32 + g * 8]);
#pragma unroll
    for (int nt = 0; nt < 3; ++nt)
      b[nt] = *reinterpret_cast<const bf16x8*>(
          &Wcat[(size_t)(jbase + wn * 48 + nt * 16 + c15) * 128 + kt * 32 + g * 8]);
#pragma unroll
    for (int mt = 0; mt < 6; ++mt)
#pragma unroll
      for (int nt = 0; nt < 3; ++nt)
        acc[mt][nt] = __builtin_amdgcn_mfma_f32_16x16x32_bf16(a[mt], b[nt], acc[mt][nt], 0, 0, 0);
  }
  const float* barr = sec == 0 ? bq : sec == 1 ? bk : sec == 2 ? bv : bg;
#pragma unroll
  for (int nt = 0; nt < 3; ++nt) {
    int col = wn * 48 + nt * 16 + c15;
    float bval = barr[(y % 3) * 96 + col];
#pragma unroll
    for (int mt = 0; mt < 6; ++mt) {
      int rbase = wm * 96 + mt * 16 + 4 * g;
#pragma unroll
      for (int i = 0; i < 4; ++i)
        Sb[(rbase + i) * 104 + col] = f2bf(acc[mt][nt][i] + bval);
    }
  }
  __syncthreads();
  if (sec == 0) {
    bf16* dst0 = q2 + ((size_t)bx * 12 + h0) * 4608;
    for (int u = t; u < 2304; u += 256) {
      int hl = u / 576, off = (u % 576) * 8;
      int ml = off / 24, c0 = off % 24;
      uint4 val = *reinterpret_cast<const uint4*>(&Sb[ml * 104 + hl * 24 + c0]);
      *reinterpret_cast<uint4*>(&dst0[(size_t)hl * 4608 + off]) = val;
    }
  } else if (sec == 3) {
    for (int u = t; u < 2304; u += 256) {
      int ml = u / 12, col = (u % 12) * 8;
      uint4 val = *reinterpret_cast<const uint4*>(&Sb[ml * 104 + col]);
      *reinterpret_cast<uint4*>(&gbuf[(size_t)(m0 + ml) * 288 + h0 * 24 + col]) = val;
    }
  } else {
    bf16* dst = (sec == 1) ? k2 : vb;
    for (int u = t; u < 2304; u += 256) {
      int hl = u / 576, off = (u % 576) * 8;
      int ml = off / 24, c0 = off % 24;
      uint4 val = *reinterpret_cast<const uint4*>(&Sb[ml * 104 + hl * 24 + c0]);
      *reinterpret_cast<uint4*>(
          &dst[(((size_t)ml * 12 + h0 + hl) * 192 + bx) * 24 + c0]) = val;
    }
  }
}

// ---------------- kernel 3: attention, role-switched (NTC: compile-time att tiles) --
// att role (la0>=0 and (lp0<0 or z==0)): wave=(bq,h); block z handles NTt l-tiles
// pv role: block=(x -> l = lp0+x, h): 4 waves split 192 b-rows; Ob bounce; gated store
template <int NTC>
__global__ __launch_bounds__(256) void k_attpv(const bf16* __restrict__ q2,
    const bf16* __restrict__ k2, const float* __restrict__ biasb,
    const bf16* __restrict__ vbuf, const bf16* __restrict__ gbuf,
    bf16* __restrict__ Patt, const bf16* __restrict__ Ppv,
    bf16* __restrict__ ogb, int la0, int lp0, int NT, int NL) {
  __shared__ __align__(16) char ldsraw[25600];
  int t = threadIdx.x;
  int w = t >> 6, lane = t & 63;
  int c15 = lane & 15, g = lane >> 4;
  const float sq_c = 0.20412414523193154f;  // 1/sqrt(24)
  bool is_att = (la0 >= 0) && (lp0 < 0 || blockIdx.z == 0);
  if (is_att) {
    int x = blockIdx.x, h = blockIdx.y;
    if (x >= 48) return;
    int bq = x * 4 + w;
    const int NTt = (NTC > 0) ? NTC : NT;
    int lbase = la0 + blockIdx.z * NTt * 16;
    u16* Sb = reinterpret_cast<u16*>(ldsraw) + (size_t)w * 3200;  // per-wave [16][200]
    const bf16* ks = &k2[((size_t)bq * 12 + h) * 4608];
    const float* bsrc = &biasb[(size_t)h * LL];
    for (int lt = 0; lt < NTt; ++lt) {
      int l0 = lbase + lt * 16;
      const bf16* qs = &q2[(((size_t)bq * 12 + h) * 192 + l0) * 24];
      bf16x8 afr = {0, 0, 0, 0, 0, 0, 0, 0};
      if (g < 3) afr = *reinterpret_cast<const bf16x8*>(&qs[c15 * 24 + g * 8]);
      f32x4 acc[12];
#pragma unroll
      for (int ct = 0; ct < 12; ++ct) {
        bf16x8 bfr = {0, 0, 0, 0, 0, 0, 0, 0};
        if (g < 3) bfr = *reinterpret_cast<const bf16x8*>(&ks[(ct * 16 + c15) * 24 + g * 8]);
        acc[ct] = __builtin_amdgcn_mfma_f32_16x16x32_bf16(afr, bfr, (f32x4){0.f, 0.f, 0.f, 0.f}, 0, 0, 0);
      }
      // bias: lane c15 reads 12 contiguous floats per row (transposed layout)
#pragma unroll
      for (int i = 0; i < 4; ++i) {
        const float* bT = &bsrc[(size_t)(l0 + 4 * g + i) * 192 + c15 * 12];
        float4 b0 = *reinterpret_cast<const float4*>(&bT[0]);
        float4 b1 = *reinterpret_cast<const float4*>(&bT[4]);
        float4 b2 = *reinterpret_cast<const float4*>(&bT[8]);
        float bb12[12] = {b0.x, b0.y, b0.z, b0.w, b1.x, b1.y, b1.z, b1.w,
                          b2.x, b2.y, b2.z, b2.w};
#pragma unroll
        for (int ct = 0; ct < 12; ++ct)
          acc[ct][i] = acc[ct][i] * sq_c + bb12[ct];
      }
      float inv[4];
#pragma unroll
      for (int i = 0; i < 4; ++i) {
        float mx = -1e30f;
#pragma unroll
        for (int ct = 0; ct < 12; ++ct) mx = fmaxf(mx, acc[ct][i]);
#pragma unroll
        for (int msk = 1; msk < 16; msk <<= 1) mx = fmaxf(mx, __shfl_xor(mx, msk, 64));
        float sm = 0.f;
#pragma unroll
        for (int ct = 0; ct < 12; ++ct) {
          float e = __expf(acc[ct][i] - mx);
          acc[ct][i] = e;
          sm += e;
        }
#pragma unroll
        for (int msk = 1; msk < 16; msk <<= 1) sm += __shfl_xor(sm, msk, 64);
        inv[i] = 1.0f / sm;
      }
#pragma unroll
      for (int i = 0; i < 4; ++i)
#pragma unroll
        for (int ct = 0; ct < 12; ++ct)
          Sb[(4 * g + i) * 200 + ct * 16 + c15] = f2bf(acc[ct][i] * inv[i]);
      int lrel = l0 - la0;
      for (int u = lane; u < 384; u += 64) {
        int lloc = u / 24, oct = u % 24;
        uint4 val = *reinterpret_cast<const uint4*>(&Sb[lloc * 200 + oct * 8]);
        *reinterpret_cast<uint4*>(
            &Patt[(((size_t)(lrel + lloc) * 12 + h) * 192 + bq) * 192 + oct * 8]) = val;
      }
    }
  } else {
    if (lp0 < 0) return;
    int x = blockIdx.x, h = blockIdx.y;
    if (x >= NL) return;
    u16* Vt = reinterpret_cast<u16*>(ldsraw);                              // [32][200]
    float* Ob = reinterpret_cast<float*>(ldsraw + 12800) + (size_t)w * 416; // [16][26]
    int l = lp0 + x;
    int lrel = x;
    const bf16* vs = &vbuf[((size_t)l * 12 + h) * 4608];
    for (int u = t; u < 576; u += 256) {
      int kk = u / 3, c0 = (u % 3) * 8;
      uint4 val = *reinterpret_cast<const uint4*>(&vs[kk * 24 + c0]);
      const u16* pv = reinterpret_cast<const u16*>(&val);
#pragma unroll
      for (int i = 0; i < 8; ++i) Vt[(c0 + i) * 200 + kk] = pv[i];
    }
    __syncthreads();
    bf16x8 bfr[6][2];
#pragma unroll
    for (int kt = 0; kt < 6; ++kt)
#pragma unroll
      for (int nt = 0; nt < 2; ++nt)
        bfr[kt][nt] = *reinterpret_cast<const bf16x8*>(
            &Vt[(nt * 16 + c15) * 200 + kt * 32 + g * 8]);
    const bf16* Ps = &Ppv[((size_t)lrel * 12 + h) * 36864];
#pragma unroll
    for (int mi = 0; mi < 3; ++mi) {
      int mt = w * 3 + mi;
      f32x4 acc0 = (f32x4){0.f, 0.f, 0.f, 0.f};
      f32x4 acc1 = (f32x4){0.f, 0.f, 0.f, 0.f};
#pragma unroll
      for (int kt = 0; kt < 6; ++kt) {
        bf16x8 a = *reinterpret_cast<const bf16x8*>(
            &Ps[(size_t)(mt * 16 + c15) * 192 + kt * 32 + g * 8]);
        acc0 = __builtin_amdgcn_mfma_f32_16x16x32_bf16(a, bfr[kt][0], acc0, 0, 0, 0);
        acc1 = __builtin_amdgcn_mfma_f32_16x16x32_bf16(a, bfr[kt][1], acc1, 0, 0, 0);
      }
#pragma unroll
      for (int i = 0; i < 4; ++i) {
        Ob[(4 * g + i) * 26 + c15] = acc0[i];
        if (c15 < 8) Ob[(4 * g + i) * 26 + 16 + c15] = acc1[i];
      }
      if (lane < 48) {
        int r = lane / 3, c0 = (lane % 3) * 8;
        int b = mt * 16 + r;
        size_t m = (size_t)b * 192 + l;
        uint4 gv4 = *reinterpret_cast<const uint4*>(&gbuf[m * 288 + h * 24 + c0]);
        const u16* gp = reinterpret_cast<const u16*>(&gv4);
        u16 opk[8];
#pragma unroll
        for (int i = 0; i < 8; ++i) {
          float av = Ob[r * 26 + c0 + i];
          float sg = 1.0f / (1.0f + __expf(-bf2f(gp[i])));
          opk[i] = f2bf(av * sg);
        }
        *reinterpret_cast<uint4*>(&ogb[m * 288 + h * 24 + c0]) = *reinterpret_cast<uint4*>(opk);
      }
    }
  }
}

// ---------------- kernel 5: out = ogb @ Wo + bo (MFMA, M-tile 64) ----------------
__global__ __launch_bounds__(256) void k_out(const bf16* __restrict__ ogb,
                                             const bf16* __restrict__ Wot,
                                             const float* __restrict__ bo,
                                             float* __restrict__ out) {
  int t = threadIdx.x;
  int w = t >> 6, lane = t & 63;
  int c15 = lane & 15, g = lane >> 4;
  int m0 = blockIdx.x * 64;
  int mrow = m0 + w * 16 + c15;
  f32x4 acc[8];
#pragma unroll
  for (int nt = 0; nt < 8; ++nt) acc[nt] = (f32x4){0.f, 0.f, 0.f, 0.f};
#pragma unroll
  for (int kt = 0; kt < 9; ++kt) {
    bf16x8 a = *reinterpret_cast<const bf16x8*>(&ogb[(size_t)mrow * 288 + kt * 32 + g * 8]);
    bf16x8 b[8];
#pragma unroll
    for (int nt = 0; nt < 8; ++nt)
      b[nt] = *reinterpret_cast<const bf16x8*>(&Wot[(size_t)(nt * 16 + c15) * 288 + kt * 32 + g * 8]);
#pragma unroll
    for (int nt = 0; nt < 8; ++nt)
      acc[nt] = __builtin_amdgcn_mfma_f32_16x16x32_bf16(a, b[nt], acc[nt], 0, 0, 0);
  }
#pragma unroll
  for (int nt = 0; nt < 8; ++nt) {
    int n = nt * 16 + c15;
    float bval = bo[n];
#pragma unroll
    for (int i = 0; i < 4; ++i) {
      int m = m0 + w * 16 + 4 * g + i;
      out[(size_t)m * 128 + n] = acc[nt][i] + bval;
    }
  }
}

extern "C" void kernel_launch(void* const* d_in, const int* in_sizes, int n_in,
                              void* d_out, int out_size, void* d_ws, size_t ws_size,
                              hipStream_t stream) {
  const float* z_in = (const float*)d_in[0];
  const float* ln_w = (const float*)d_in[1];
  const float* ln_b = (const float*)d_in[2];
  const float* Wq   = (const float*)d_in[3];
  const float* bq   = (const float*)d_in[4];
  const float* Wk   = (const float*)d_in[5];
  const float* bk   = (const float*)d_in[6];
  const float* Wv   = (const float*)d_in[7];
  const float* bv   = (const float*)d_in[8];
  const float* Wb   = (const float*)d_in[9];
  const float* bb   = (const float*)d_in[10];
  const float* Wg   = (const float*)d_in[11];
  const float* bg   = (const float*)d_in[12];
  const float* Wo   = (const float*)d_in[13];
  const float* bo   = (const float*)d_in[14];
  float* out = (float*)d_out;

  char* ws = (char*)d_ws;

  if (ws_size >= 256573440ull) {
    // ---- full-P compact plan ----
    bf16* q2    = (bf16*)(ws + 0);            // [b][h][l][24]; ogb aliases after att
    bf16* ogb   = (bf16*)(ws + 0);
    bf16* k2    = (bf16*)(ws + 21233664);     // [b][h][kk][24]
    bf16* vb    = (bf16*)(ws + 42467328);     // [l][h][kk][24]
    bf16* gbuf  = (bf16*)(ws + 63700992);     // [m][288]
    float* biasb = (float*)(ws + 84934656);   // [12][192][192] f32 (transposed-in-16)
    bf16* P     = (bf16*)(ws + 86704128);     // [l][h][b][kk] full
    bf16* zb    = (bf16*)(ws + 86704128);     // union in P: dead after k_proj
    bf16* Wcat  = (bf16*)(ws + 96141312);     // union in P: dead after k_proj
    bf16* Wot   = (bf16*)(ws + 86704128);     // union in P: written after pv

    k_cvt<<<dim3(72), dim3(256), 0, stream>>>(Wq, Wk, Wv, Wg, Wcat);
    k_ln<<<dim3(9216), dim3(256), 0, stream>>>(z_in, ln_w, ln_b, zb);
    k_bias<<<dim3(576), dim3(256), 0, stream>>>(zb, Wb, bb, biasb);
    k_proj<<<dim3(192, 12), dim3(256), 0, stream>>>(zb, Wcat, bq, bk, bv, bg,
                                                    q2, k2, vb, gbuf);
    // att split over z: 4 z-slices x 3 l-tiles (compile-time NTC=3) -> 2304 blocks
    k_attpv<3><<<dim3(48, 12, 4), dim3(256), 0, stream>>>(
        q2, k2, biasb, vb, gbuf, P, P, ogb, 0, -1, 3, 192);
    k_attpv<0><<<dim3(192, 12, 1), dim3(256), 0, stream>>>(
        q2, k2, biasb, vb, gbuf, P, P, ogb, -1, 0, 12, 192);
    k_cvt2<<<dim3(18), dim3(256), 0, stream>>>(Wo, Wot);
    k_out<<<dim3(576), dim3(256), 0, stream>>>(ogb, Wot, bo, out);
    return;
  }

  // ---- fallback: round-10 proven layout & ladder ----
  bf16* q2    = (bf16*)(ws + 0);            // [b][h][l][24]
  bf16* k2    = (bf16*)(ws + 21233664);     // [b][h][kk][24]
  bf16* vb    = (bf16*)(ws + 42467328);     // [l][h][kk][24]
  bf16* gbuf  = (bf16*)(ws + 63700992);     // [m][288]
  bf16* ogb   = (bf16*)(ws + 84934656);     // [m][288]
  bf16* zb    = (bf16*)(ws + 84934656);     // union: dead after k_proj
  bf16* Wcat  = (bf16*)(ws + 94371840);     // union in ogb: dead after k_proj
  float* biasb = (float*)(ws + 106168320);  // [12][192][192] f32
  char* Pbase = ws + 107937792;
  bf16* Wot   = (bf16*)(ws + 107937792);    // union with P (written after pv loop)

  k_cvt<<<dim3(72), dim3(256), 0, stream>>>(Wq, Wk, Wv, Wg, Wcat);
  k_ln<<<dim3(9216), dim3(256), 0, stream>>>(z_in, ln_w, ln_b, zb);
  k_bias<<<dim3(576), dim3(256), 0, stream>>>(zb, Wb, bb, biasb);
  k_proj<<<dim3(192, 12), dim3(256), 0, stream>>>(zb, Wcat, bq, bk, bv, bg,
                                                  q2, k2, vb, gbuf);
  const size_t PB = 107937792ull;
  int CL;
  if      (ws_size >= PB + 84934656ull)  CL = 48;   // dbuf 48
  else if (ws_size >= PB + 56623104ull)  CL = 32;   // dbuf 32
  else if (ws_size >= PB + 28311552ull)  CL = 16;   // dbuf 16
  else                                   CL = -16;  // serial 16, single buffer
  if (CL > 0) {
    int nch = 192 / CL;
    size_t csz = (size_t)CL * 884736ull;  // CL*12*192*192*2 bytes
    bf16* P0 = (bf16*)Pbase;
    bf16* P1 = (bf16*)(Pbase + csz);
    int NT = CL / 16;
    for (int n = 0; n <= nch; ++n) {
      bf16* Pa = (n & 1) ? P1 : P0;
      bf16* Pp = ((n - 1) & 1) ? P1 : P0;
      int la = (n < nch) ? n * CL : -1;
      int lp = (n >= 1) ? (n - 1) * CL : -1;
      if (la >= 0 && lp >= 0)
        k_attpv<0><<<dim3(48 > CL ? 48 : CL, 12, 2), dim3(256), 0, stream>>>(
            q2, k2, biasb, vb, gbuf, Pa, Pp, ogb, la, lp, NT, CL);
      else if (la >= 0)
        k_attpv<0><<<dim3(48, 12, 1), dim3(256), 0, stream>>>(
            q2, k2, biasb, vb, gbuf, Pa, Pp, ogb, la, -1, NT, CL);
      else
        k_attpv<0><<<dim3(CL, 12, 1), dim3(256), 0, stream>>>(
            q2, k2, biasb, vb, gbuf, Pa, Pp, ogb, -1, lp, NT, CL);
    }
  } else {
    bf16* P0 = (bf16*)Pbase;
    for (int n = 0; n < 12; ++n) {
      k_attpv<0><<<dim3(48, 12, 1), dim3(256), 0, stream>>>(
          q2, k2, biasb, vb, gbuf, P0, P0, ogb, n * 16, -1, 1, 16);
      k_attpv<0><<<dim3(16, 12, 1), dim3(256), 0, stream>>>(
          q2, k2, biasb, vb, gbuf, P0, P0, ogb, -1, n * 16, 1, 16);
    }
  }
  k_cvt2<<<dim3(18), dim3(256), 0, stream>>>(Wo, Wot);
  k_out<<<dim3(576), dim3(256), 0, stream>>>(ogb, Wot, bo, out);
}